// Round 19
// baseline (47.768 us; speedup 1.0000x reference)
//
#include <hip/hip_runtime.h>

#define NQ    14
#define NPAR  196
#define NCLS  10

// ============================================================================
// MPS/Heisenberg formulation (r19).
// psi2 = C2*U2*C1*U1*C0*U0|0>  is the HW-verified chi=4 TT (r14/r16):
//   psi2[h] = sum_{j2,j} prod_s V2[gh_s,j2_s] V1[j2_s^j2_{s+1}, j_s] phi[j_s^j_{s+1}]
//   with gh = h ^ (h>>1), j*_14 = 0, free sum at s=0.
// As an MPS over PHYSICAL bits h_s (carry c = h_{s+1} on the bond, chi=8), with
// U3 absorbed:  At_s[h][(j2p,jp,c),(j2,j,cp)] =
//      u3[h,cp] * V2[cp^c, j2] * V1[j2^j2p, j] * phi[j^jp]
// (at u3=I, row (0,0,0) reproduces the verified W13 = V2[b13,c2]V1[c2,c]phi[c]).
// psi3[h] = e_0^T At_13[h13] ... At_0[h0] 1vec.
// Heisenberg tail:  E_q = <psi3| C3^dag (u4^dag Z u4) C3 |psi3>.  Pauli
// propagation through the CNOT staircase (ctrl bit b, tgt b-1; conjugation
// order G_1..G_13) gives, with M = u4^dag Z u4 = aI+bX+cY+dZ and b = 13-q:
//   O_q = a*I + b*X_b X_{b-1} + c*(Z_13..Z_{b+1}) Y_b X_{b-1}
//       + d*(Z_13..Z_{b+1}) Z_b          (X_{b-1} absent for b=0)
// Sandwich via 8x8 transfer sweeps:
//   L-step:  L' = sum_{h',h} op[h',h] At[h']^dag L At[h]   (top-down, s=13..0)
//   P-step:  P' = sum_h conj(At[h]) P At[h]^T              (bottom-up, s=0..13)
//   merge at a cut: E = sum_{ij} L[i,j] * P[i,j]
// ============================================================================

__device__ __forceinline__ float2 cmul(float2 a, float2 b) {
    return make_float2(a.x*b.x - a.y*b.y, a.x*b.y + a.y*b.x);
}
__device__ __forceinline__ float2 cmulc(float2 a, float2 b) {   // conj(a)*b
    return make_float2(a.x*b.x + a.y*b.y, a.x*b.y - a.y*b.x);
}
__device__ __forceinline__ float2 cadd(float2 a, float2 b) {
    return make_float2(a.x + b.x, a.y + b.y);
}
__device__ __forceinline__ float2 csub(float2 a, float2 b) {
    return make_float2(a.x - b.x, a.y - b.y);
}

__global__ void __launch_bounds__(256)
qvc_mps(const float* __restrict__ x, const float* __restrict__ Wm,
        const float* __restrict__ bias, float* __restrict__ out)
{
    __shared__ float  uc[70][8];
    __shared__ float2 At[14][2][64];   // site s, phys h, 8x8 [row*8+col]
    __shared__ float2 LI[15][64];      // L^I after sites 13..s  (LI[14]=base)
    __shared__ float2 LZ[15][64];      // L^Z prefix
    __shared__ float2 Ps[14][64];      // Ps[t] = P after sites 0..t-1 (Ps[0]=ones)
    __shared__ float2 scr[3][2][64];
    __shared__ float2 cmat[3][64];
    __shared__ float  abcd[NQ][4];
    __shared__ float  Eq[NQ];
    __shared__ float  Tv[3];           // Tz, Tx, Ty for current q

    const int e = blockIdx.x;
    const int tid = threadIdx.x;
    const int wave = tid >> 6, lane = tid & 63;
    const int i8 = lane >> 3, j8 = lane & 7;
    const float* xb = x + e * NPAR;

    // ---- all 70 gate 2x2s (verified code) ----
    if (tid < 70) {
        const int layer = tid / 14, q = tid % 14;
        const int pidx = (layer < 4) ? layer * 42 + q * 3 : 168 + q * 2;
        float a1 = 0.5f * xb[pidx], a2 = 0.5f * xb[pidx + 1];
        float s1, c1, s2, c2;
        sincosf(a1, &s1, &c1);
        sincosf(a2, &s2, &c2);
        float A00r =  c2 * c1, A00i =  s2 * s1;
        float A01r = -s2 * c1, A01i = -c2 * s1;
        float A10r =  s2 * c1, A10i = -c2 * s1;
        float A11r =  c2 * c1, A11i = -s2 * s1;
        float U0, U1, U2, U3, U4, U5, U6, U7;
        if (layer < 4) {
            float a3 = 0.5f * xb[pidx + 2]; float s3, c3; sincosf(a3, &s3, &c3);
            U0 = c3 * A00r + s3 * A00i; U1 = c3 * A00i - s3 * A00r;
            U2 = c3 * A01r + s3 * A01i; U3 = c3 * A01i - s3 * A01r;
            U4 = c3 * A10r - s3 * A10i; U5 = c3 * A10i + s3 * A10r;
            U6 = c3 * A11r - s3 * A11i; U7 = c3 * A11i + s3 * A11r;
        } else {
            U0 = A00r; U1 = A00i; U2 = A01r; U3 = A01i;
            U4 = A10r; U5 = A10i; U6 = A11r; U7 = A11i;
        }
        uc[tid][0] = U0; uc[tid][1] = U1; uc[tid][2] = U2; uc[tid][3] = U3;
        uc[tid][4] = U4; uc[tid][5] = U5; uc[tid][6] = U6; uc[tid][7] = U7;
    }
    __syncthreads();

    // ---- Pauli coefficients of M_q = u4^dag Z u4 = aI+bX+cY+dZ ----
    if (tid < NQ) {
        const float* g = uc[56 + tid];
        float2 A00 = {g[0], g[1]}, A01 = {g[2], g[3]};
        float2 A10 = {g[4], g[5]}, A11 = {g[6], g[7]};
        float M00 = A00.x*A00.x + A00.y*A00.y - (A10.x*A10.x + A10.y*A10.y);
        float M11 = A01.x*A01.x + A01.y*A01.y - (A11.x*A11.x + A11.y*A11.y);
        float2 M01 = csub(cmulc(A00, A01), cmulc(A10, A11));   // = b - i c
        abcd[tid][0] = 0.5f * (M00 + M11);
        abcd[tid][1] = M01.x;
        abcd[tid][2] = -M01.y;
        abcd[tid][3] = 0.5f * (M00 - M11);
    }

    // ---- build site tensors At ----
    for (int idx = tid; idx < 14 * 2 * 64; idx += 256) {
        const int s = idx >> 7, h = (idx >> 6) & 1, ent = idx & 63;
        const int i = ent >> 3, j = ent & 7;
        const int j2p = i >> 2, jp = (i >> 1) & 1, cb = i & 1;
        const int j2  = j >> 2, jv = (j >> 1) & 1, cp = j & 1;
        const int q = 13 - s;
        const float* u3 = uc[42 + q];
        const float* V2 = uc[28 + q];
        const float* V1 = uc[14 + q];
        const float* ph = uc[q];
        float2 f1 = {u3[h*4 + cp*2],           u3[h*4 + cp*2 + 1]};
        float2 f2 = {V2[(cp^cb)*4 + j2*2],     V2[(cp^cb)*4 + j2*2 + 1]};
        float2 f3 = {V1[(j2^j2p)*4 + jv*2],    V1[(j2^j2p)*4 + jv*2 + 1]};
        float2 f4 = {ph[(jv^jp)*4],            ph[(jv^jp)*4 + 1]};
        At[s][h][ent] = cmul(cmul(f1, f2), cmul(f3, f4));
    }
    if (tid < 64) {
        LI[14][tid] = make_float2(tid == 0 ? 1.0f : 0.0f, 0.0f);
        LZ[14][tid] = LI[14][tid];
        Ps[0][tid]  = make_float2(1.0f, 0.0f);
    }
    __syncthreads();

    // ---- sweeps: wave0 = L^I (site 13-t), wave1 = L^Z, wave2 = P (site t) ----
    for (int t = 0; t < 14; ++t) {
        if (wave == 0 || wave == 1) {
            const int s = 13 - t;
            const float2* L = (wave == 0) ? LI[s + 1] : LZ[s + 1];
            float2 b0 = {0,0}, b1 = {0,0};
            #pragma unroll
            for (int l = 0; l < 8; ++l) {
                b0 = cadd(b0, cmul(L[i8*8 + l], At[s][0][l*8 + j8]));
                b1 = cadd(b1, cmul(L[i8*8 + l], At[s][1][l*8 + j8]));
            }
            scr[wave][0][lane] = b0; scr[wave][1][lane] = b1;
        } else if (wave == 2) {
            const int s = t;
            const float2* P = Ps[s];
            float2 c0 = {0,0}, c1 = {0,0};
            #pragma unroll
            for (int l = 0; l < 8; ++l) {       // C_h = P * At[h]^T
                c0 = cadd(c0, cmul(P[i8*8 + l], At[s][0][j8*8 + l]));
                c1 = cadd(c1, cmul(P[i8*8 + l], At[s][1][j8*8 + l]));
            }
            scr[2][0][lane] = c0; scr[2][1][lane] = c1;
        }
        __syncthreads();
        if (wave == 0 || wave == 1) {
            const int s = 13 - t;
            float2 acc = {0,0};
            #pragma unroll
            for (int k = 0; k < 8; ++k) {
                float2 t0 = cmulc(At[s][0][k*8 + i8], scr[wave][0][k*8 + j8]);
                float2 t1 = cmulc(At[s][1][k*8 + i8], scr[wave][1][k*8 + j8]);
                acc = cadd(acc, (wave == 0) ? cadd(t0, t1) : csub(t0, t1));
            }
            ((wave == 0) ? LI[s] : LZ[s])[lane] = acc;
        } else if (wave == 2) {
            const int s = t;
            float2 acc = {0,0};
            #pragma unroll
            for (int k = 0; k < 8; ++k) {
                acc = cadd(acc, cmulc(At[s][0][i8*8 + k], scr[2][0][k*8 + j8]));
                acc = cadd(acc, cmulc(At[s][1][i8*8 + k], scr[2][1][k*8 + j8]));
            }
            if (s + 1 < 14) Ps[s + 1][lane] = acc;
        }
        __syncthreads();
    }

    // ---- centers: per q, waves compute Tz / Tx / Ty ----
    for (int q = 0; q < NQ; ++q) {
        const int b = 13 - q;
        if (wave == 0) {          // Tz: Z-step of LZ[b+1] at site b
            float2 b0 = {0,0}, b1 = {0,0};
            #pragma unroll
            for (int l = 0; l < 8; ++l) {
                b0 = cadd(b0, cmul(LZ[b+1][i8*8 + l], At[b][0][l*8 + j8]));
                b1 = cadd(b1, cmul(LZ[b+1][i8*8 + l], At[b][1][l*8 + j8]));
            }
            scr[0][0][lane] = b0; scr[0][1][lane] = b1;
        } else if (wave == 1) {   // Tx: X-step of LI[b+1] at site b
            float2 b0 = {0,0}, b1 = {0,0};
            #pragma unroll
            for (int l = 0; l < 8; ++l) {
                b0 = cadd(b0, cmul(LI[b+1][i8*8 + l], At[b][1][l*8 + j8]));
                b1 = cadd(b1, cmul(LI[b+1][i8*8 + l], At[b][0][l*8 + j8]));
            }
            scr[1][0][lane] = b0; scr[1][1][lane] = b1;
        } else if (wave == 2) {   // Ty: Y-step of LZ[b+1] at site b
            float2 b0 = {0,0}, b1 = {0,0};
            #pragma unroll
            for (int l = 0; l < 8; ++l) {
                b0 = cadd(b0, cmul(LZ[b+1][i8*8 + l], At[b][1][l*8 + j8]));
                b1 = cadd(b1, cmul(LZ[b+1][i8*8 + l], At[b][0][l*8 + j8]));
            }
            scr[2][0][lane] = b0; scr[2][1][lane] = b1;
        }
        __syncthreads();
        if (wave == 0) {
            float2 acc = {0,0};
            #pragma unroll
            for (int k = 0; k < 8; ++k) {
                acc = cadd(acc, cmulc(At[b][0][k*8 + i8], scr[0][0][k*8 + j8]));
                acc = csub(acc, cmulc(At[b][1][k*8 + i8], scr[0][1][k*8 + j8]));
            }
            cmat[0][lane] = acc;
        } else if (wave == 1) {
            float2 acc = {0,0};
            #pragma unroll
            for (int k = 0; k < 8; ++k) {
                acc = cadd(acc, cmulc(At[b][0][k*8 + i8], scr[1][0][k*8 + j8]));
                acc = cadd(acc, cmulc(At[b][1][k*8 + i8], scr[1][1][k*8 + j8]));
            }
            cmat[1][lane] = acc;
        } else if (wave == 2) {
            float2 a0 = {0,0}, a1 = {0,0};
            #pragma unroll
            for (int k = 0; k < 8; ++k) {
                a0 = cadd(a0, cmulc(At[b][0][k*8 + i8], scr[2][0][k*8 + j8]));
                a1 = cadd(a1, cmulc(At[b][1][k*8 + i8], scr[2][1][k*8 + j8]));
            }
            float2 d = csub(a1, a0);                // -i*a0 + i*a1 = i*(a1-a0)
            cmat[2][lane] = make_float2(-d.y, d.x);
        }
        __syncthreads();
        if (b >= 1) {            // X at site b-1 for Tx, Ty
            if (wave == 1 || wave == 2) {
                const float2* L2 = cmat[wave];
                float2 b0 = {0,0}, b1 = {0,0};
                #pragma unroll
                for (int l = 0; l < 8; ++l) {
                    b0 = cadd(b0, cmul(L2[i8*8 + l], At[b-1][1][l*8 + j8]));
                    b1 = cadd(b1, cmul(L2[i8*8 + l], At[b-1][0][l*8 + j8]));
                }
                scr[wave][0][lane] = b0; scr[wave][1][lane] = b1;
            }
            __syncthreads();
            if (wave == 1 || wave == 2) {
                float2 acc = {0,0};
                #pragma unroll
                for (int k = 0; k < 8; ++k) {
                    acc = cadd(acc, cmulc(At[b-1][0][k*8 + i8], scr[wave][0][k*8 + j8]));
                    acc = cadd(acc, cmulc(At[b-1][1][k*8 + i8], scr[wave][1][k*8 + j8]));
                }
                cmat[wave][lane] = acc;
            }
            __syncthreads();
        }
        if (wave < 3) {          // contract with suffix; real part
            const float2* P = (wave == 0) ? Ps[b] : Ps[(b >= 1) ? (b - 1) : 0];
            float v = cmat[wave][lane].x * P[lane].x - cmat[wave][lane].y * P[lane].y;
            #pragma unroll
            for (int off = 32; off > 0; off >>= 1) v += __shfl_down(v, off, 64);
            if (lane == 0) Tv[wave] = v;
        }
        __syncthreads();
        if (tid == 0)
            Eq[q] = abcd[q][0] + abcd[q][1] * Tv[1]
                  + abcd[q][2] * Tv[2] + abcd[q][3] * Tv[0];
        __syncthreads();
    }

    // ---- head ----
    if (tid < NCLS) {
        float acc = bias[tid];
        #pragma unroll
        for (int qq = 0; qq < NQ; ++qq) acc += Wm[tid * NQ + qq] * Eq[qq];
        out[e * NCLS + tid] = acc;
    }
}

extern "C" void kernel_launch(void* const* d_in, const int* in_sizes, int n_in,
                              void* d_out, int out_size, void* d_ws, size_t ws_size,
                              hipStream_t stream)
{
    const float* x    = (const float*)d_in[0];   // (64, 196)
    const float* W    = (const float*)d_in[1];   // (10, 14)
    const float* bias = (const float*)d_in[2];   // (10,)
    float*       out  = (float*)d_out;           // (64, 10)
    (void)d_ws; (void)ws_size;                   // no workspace needed

    hipLaunchKernelGGL(qvc_mps, dim3(64), dim3(256), 0, stream, x, W, bias, out);
}

// Round 20
// 34.812 us; speedup vs baseline: 1.3722x; 1.3722x over previous
//
#include <hip/hip_runtime.h>

#define NQ    14
#define NPAR  196
#define NCLS  10

// ============================================================================
// MPS/Heisenberg formulation — algebra verified on HW in r19 (absmax 0).
// This round: same arithmetic, barrier-free data movement.
//   - each wave's 64 lanes hold one 8x8 complex matrix (lane = i*8+j)
//   - matmul stages use __shfl gathers + read-only LDS At -> NO __syncthreads
//   - 3 transfer sweeps = independent single-wave register chains
//   - 42 center tasks (14 q x 3 terms) fully parallel across 16 waves
// psi2 = chi=4 TT (r14/r16-verified); U3 absorbed into chi=8 site tensors At;
// Heisenberg tail: O_q = a I + b X_b X_{b-1} + c (Z..Z) Y_b X_{b-1} + d (Z..Z) Z_b.
// ============================================================================

__device__ __forceinline__ float2 cmul(float2 a, float2 b) {
    return make_float2(a.x*b.x - a.y*b.y, a.x*b.y + a.y*b.x);
}
__device__ __forceinline__ float2 cmulc(float2 a, float2 b) {   // conj(a)*b
    return make_float2(a.x*b.x + a.y*b.y, a.x*b.y - a.y*b.x);
}
__device__ __forceinline__ float2 cadd(float2 a, float2 b) {
    return make_float2(a.x + b.x, a.y + b.y);
}
__device__ __forceinline__ float2 csub(float2 a, float2 b) {
    return make_float2(a.x - b.x, a.y - b.y);
}
__device__ __forceinline__ float2 shfl2(float2 v, int src) {
    return make_float2(__shfl(v.x, src, 64), __shfl(v.y, src, 64));
}

__global__ void __launch_bounds__(1024)
qvc_mps(const float* __restrict__ x, const float* __restrict__ Wm,
        const float* __restrict__ bias, float* __restrict__ out)
{
    __shared__ float  uc[70][8];
    __shared__ float2 At[14][2][64];   // site s, phys h, 8x8 [row*8+col]
    __shared__ float2 LI[15][64];      // L^I prefixes (LI[14] = base)
    __shared__ float2 LZ[15][64];      // L^Z prefixes
    __shared__ float2 Ps[14][64];      // Ps[t] = P after sites 0..t-1 (Ps[0]=ones)
    __shared__ float  abcd[NQ][4];
    __shared__ float  Tv2[NQ][3];      // Tz, Tx, Ty per q
    __shared__ float  Eq[NQ];

    const int e = blockIdx.x;
    const int tid = threadIdx.x;
    const int wave = tid >> 6, lane = tid & 63;
    const int i8 = lane >> 3, j8 = lane & 7;
    const float* xb = x + e * NPAR;

    // ---- all 70 gate 2x2s (verified) ----
    if (tid < 70) {
        const int layer = tid / 14, q = tid % 14;
        const int pidx = (layer < 4) ? layer * 42 + q * 3 : 168 + q * 2;
        float a1 = 0.5f * xb[pidx], a2 = 0.5f * xb[pidx + 1];
        float s1, c1, s2, c2;
        sincosf(a1, &s1, &c1);
        sincosf(a2, &s2, &c2);
        float A00r =  c2 * c1, A00i =  s2 * s1;
        float A01r = -s2 * c1, A01i = -c2 * s1;
        float A10r =  s2 * c1, A10i = -c2 * s1;
        float A11r =  c2 * c1, A11i = -s2 * s1;
        float U0, U1, U2, U3, U4, U5, U6, U7;
        if (layer < 4) {
            float a3 = 0.5f * xb[pidx + 2]; float s3, c3; sincosf(a3, &s3, &c3);
            U0 = c3 * A00r + s3 * A00i; U1 = c3 * A00i - s3 * A00r;
            U2 = c3 * A01r + s3 * A01i; U3 = c3 * A01i - s3 * A01r;
            U4 = c3 * A10r - s3 * A10i; U5 = c3 * A10i + s3 * A10r;
            U6 = c3 * A11r - s3 * A11i; U7 = c3 * A11i + s3 * A11r;
        } else {
            U0 = A00r; U1 = A00i; U2 = A01r; U3 = A01i;
            U4 = A10r; U5 = A10i; U6 = A11r; U7 = A11i;
        }
        uc[tid][0] = U0; uc[tid][1] = U1; uc[tid][2] = U2; uc[tid][3] = U3;
        uc[tid][4] = U4; uc[tid][5] = U5; uc[tid][6] = U6; uc[tid][7] = U7;
    }
    __syncthreads();

    // ---- Pauli coefficients of M_q = u4^dag Z u4 (verified r19) ----
    if (tid < NQ) {
        const float* g = uc[56 + tid];
        float2 A00 = {g[0], g[1]}, A01 = {g[2], g[3]};
        float2 A10 = {g[4], g[5]}, A11 = {g[6], g[7]};
        float M00 = A00.x*A00.x + A00.y*A00.y - (A10.x*A10.x + A10.y*A10.y);
        float M11 = A01.x*A01.x + A01.y*A01.y - (A11.x*A11.x + A11.y*A11.y);
        float2 M01 = csub(cmulc(A00, A01), cmulc(A10, A11));   // = b - i c
        abcd[tid][0] = 0.5f * (M00 + M11);
        abcd[tid][1] = M01.x;
        abcd[tid][2] = -M01.y;
        abcd[tid][3] = 0.5f * (M00 - M11);
    }

    // ---- site tensors At (verified r19) ----
    for (int idx = tid; idx < 14 * 2 * 64; idx += 1024) {
        const int s = idx >> 7, h = (idx >> 6) & 1, ent = idx & 63;
        const int i = ent >> 3, j = ent & 7;
        const int j2p = i >> 2, jp = (i >> 1) & 1, cb = i & 1;
        const int j2  = j >> 2, jv = (j >> 1) & 1, cp = j & 1;
        const int q = 13 - s;
        const float* u3 = uc[42 + q];
        const float* V2 = uc[28 + q];
        const float* V1 = uc[14 + q];
        const float* ph = uc[q];
        float2 f1 = {u3[h*4 + cp*2],           u3[h*4 + cp*2 + 1]};
        float2 f2 = {V2[(cp^cb)*4 + j2*2],     V2[(cp^cb)*4 + j2*2 + 1]};
        float2 f3 = {V1[(j2^j2p)*4 + jv*2],    V1[(j2^j2p)*4 + jv*2 + 1]};
        float2 f4 = {ph[(jv^jp)*4],            ph[(jv^jp)*4 + 1]};
        At[s][h][ent] = cmul(cmul(f1, f2), cmul(f3, f4));
    }
    if (tid < 64) {
        LI[14][tid] = make_float2(tid == 0 ? 1.0f : 0.0f, 0.0f);
        LZ[14][tid] = LI[14][tid];
        Ps[0][tid]  = make_float2(1.0f, 0.0f);
    }
    __syncthreads();

    // ---- sweeps: wave0 = L^I, wave1 = L^Z (top-down), wave2 = P (bottom-up).
    // Barrier-free: in-wave shuffles; prefixes stored for the center phase.
    if (wave == 0 || wave == 1) {
        float2 L = make_float2(lane == 0 ? 1.0f : 0.0f, 0.0f);
        for (int t = 0; t < 14; ++t) {
            const int s = 13 - t;
            float2 B0 = {0,0}, B1 = {0,0};
            #pragma unroll
            for (int l = 0; l < 8; ++l) {
                float2 Ll = shfl2(L, i8*8 + l);
                B0 = cadd(B0, cmul(Ll, At[s][0][l*8 + j8]));
                B1 = cadd(B1, cmul(Ll, At[s][1][l*8 + j8]));
            }
            float2 acc = {0,0};
            #pragma unroll
            for (int k = 0; k < 8; ++k) {
                float2 t0 = cmulc(At[s][0][k*8 + i8], shfl2(B0, k*8 + j8));
                float2 t1 = cmulc(At[s][1][k*8 + i8], shfl2(B1, k*8 + j8));
                acc = cadd(acc, (wave == 0) ? cadd(t0, t1) : csub(t0, t1));
            }
            L = acc;
            ((wave == 0) ? LI[s] : LZ[s])[lane] = L;
        }
    } else if (wave == 2) {
        float2 P = make_float2(1.0f, 0.0f);
        for (int s = 0; s < 14; ++s) {
            float2 D0 = {0,0}, D1 = {0,0};
            #pragma unroll
            for (int l = 0; l < 8; ++l) {
                float2 Pl = shfl2(P, i8*8 + l);
                D0 = cadd(D0, cmul(Pl, At[s][0][j8*8 + l]));
                D1 = cadd(D1, cmul(Pl, At[s][1][j8*8 + l]));
            }
            float2 acc = {0,0};
            #pragma unroll
            for (int k = 0; k < 8; ++k) {
                acc = cadd(acc, cmulc(At[s][0][i8*8 + k], shfl2(D0, k*8 + j8)));
                acc = cadd(acc, cmulc(At[s][1][i8*8 + k], shfl2(D1, k*8 + j8)));
            }
            P = acc;
            if (s + 1 < 14) Ps[s + 1][lane] = P;
        }
    }
    __syncthreads();

    // ---- 42 center tasks (q, term): term 0=Tz, 1=Tx, 2=Ty; all in parallel ----
    for (int round = 0; round < 3; ++round) {
        const int tk = wave + 16 * round;
        if (tk < 42) {
            const int q = tk / 3, term = tk % 3, b = 13 - q;
            float2 Lr = (term == 1) ? LI[b+1][lane] : LZ[b+1][lane];
            // stage at site b (Z: same-h; X/Y: swapped-h ket side)
            float2 B0 = {0,0}, B1 = {0,0};
            #pragma unroll
            for (int l = 0; l < 8; ++l) {
                float2 Ll = shfl2(Lr, i8*8 + l);
                if (term == 0) {
                    B0 = cadd(B0, cmul(Ll, At[b][0][l*8 + j8]));
                    B1 = cadd(B1, cmul(Ll, At[b][1][l*8 + j8]));
                } else {
                    B0 = cadd(B0, cmul(Ll, At[b][1][l*8 + j8]));
                    B1 = cadd(B1, cmul(Ll, At[b][0][l*8 + j8]));
                }
            }
            float2 cm;
            if (term == 0) {
                float2 acc = {0,0};
                #pragma unroll
                for (int k = 0; k < 8; ++k) {
                    acc = cadd(acc, cmulc(At[b][0][k*8 + i8], shfl2(B0, k*8 + j8)));
                    acc = csub(acc, cmulc(At[b][1][k*8 + i8], shfl2(B1, k*8 + j8)));
                }
                cm = acc;
            } else if (term == 1) {
                float2 acc = {0,0};
                #pragma unroll
                for (int k = 0; k < 8; ++k) {
                    acc = cadd(acc, cmulc(At[b][0][k*8 + i8], shfl2(B0, k*8 + j8)));
                    acc = cadd(acc, cmulc(At[b][1][k*8 + i8], shfl2(B1, k*8 + j8)));
                }
                cm = acc;
            } else {
                float2 a0 = {0,0}, a1 = {0,0};
                #pragma unroll
                for (int k = 0; k < 8; ++k) {
                    a0 = cadd(a0, cmulc(At[b][0][k*8 + i8], shfl2(B0, k*8 + j8)));
                    a1 = cadd(a1, cmulc(At[b][1][k*8 + i8], shfl2(B1, k*8 + j8)));
                }
                float2 d = csub(a1, a0);            // i*(a1-a0)
                cm = make_float2(-d.y, d.x);
            }
            // X-step at site b-1 for Tx, Ty
            if (term >= 1 && b >= 1) {
                float2 C0 = {0,0}, C1 = {0,0};
                #pragma unroll
                for (int l = 0; l < 8; ++l) {
                    float2 Ll = shfl2(cm, i8*8 + l);
                    C0 = cadd(C0, cmul(Ll, At[b-1][1][l*8 + j8]));
                    C1 = cadd(C1, cmul(Ll, At[b-1][0][l*8 + j8]));
                }
                float2 acc = {0,0};
                #pragma unroll
                for (int k = 0; k < 8; ++k) {
                    acc = cadd(acc, cmulc(At[b-1][0][k*8 + i8], shfl2(C0, k*8 + j8)));
                    acc = cadd(acc, cmulc(At[b-1][1][k*8 + i8], shfl2(C1, k*8 + j8)));
                }
                cm = acc;
            }
            // contract with suffix; real part; in-wave reduce
            const float2* P = (term == 0) ? Ps[b] : Ps[(b >= 1) ? (b - 1) : 0];
            float v = cm.x * P[lane].x - cm.y * P[lane].y;
            #pragma unroll
            for (int off = 32; off > 0; off >>= 1) v += __shfl_down(v, off, 64);
            if (lane == 0) Tv2[q][term] = v;
        }
    }
    __syncthreads();

    if (tid < NQ)
        Eq[tid] = abcd[tid][0] + abcd[tid][1] * Tv2[tid][1]
                + abcd[tid][2] * Tv2[tid][2] + abcd[tid][3] * Tv2[tid][0];
    __syncthreads();

    // ---- head ----
    if (tid < NCLS) {
        float acc = bias[tid];
        #pragma unroll
        for (int qq = 0; qq < NQ; ++qq) acc += Wm[tid * NQ + qq] * Eq[qq];
        out[e * NCLS + tid] = acc;
    }
}

extern "C" void kernel_launch(void* const* d_in, const int* in_sizes, int n_in,
                              void* d_out, int out_size, void* d_ws, size_t ws_size,
                              hipStream_t stream)
{
    const float* x    = (const float*)d_in[0];   // (64, 196)
    const float* W    = (const float*)d_in[1];   // (10, 14)
    const float* bias = (const float*)d_in[2];   // (10,)
    float*       out  = (float*)d_out;           // (64, 10)
    (void)d_ws; (void)ws_size;                   // no workspace needed

    hipLaunchKernelGGL(qvc_mps, dim3(64), dim3(1024), 0, stream, x, W, bias, out);
}